// Round 10
// baseline (211.529 us; speedup 1.0000x reference)
//
#include <hip/hip_runtime.h>

#define M_DIM 16384
#define N_DIM 1024
#define K_DIM 4096

#define BM 256
#define BN 256
#define BK 64
#define NT (K_DIM / BK)

typedef __attribute__((ext_vector_type(4))) float f32x4;
typedef __attribute__((ext_vector_type(8))) short bf16x8;
typedef __attribute__((ext_vector_type(8))) unsigned short u16x8;

static __device__ __forceinline__ short f2bf(float f) {
  union { __bf16 h; short s; } u;
  u.h = (__bf16)f;   // RNE; pairs pack into v_cvt_pk_bf16_f32
  return u.s;
}

// ---------- prepass: WbT[n][k] = bf16(sign(W[k][n])) ----------
__global__ __launch_bounds__(256) void wsign_transpose(
    const float* __restrict__ W, unsigned short* __restrict__ WbT) {
  __shared__ unsigned short tile[64][67];
  const int t  = (int)threadIdx.x;
  const int k0 = (int)(blockIdx.x >> 4) * 64;
  const int n0 = (int)(blockIdx.x & 15) * 64;
#pragma unroll
  for (int p = 0; p < 4; ++p) {
    const int r = p * 16 + (t >> 4);
    const int c = (t & 15) * 4;
    const float* src = W + (size_t)(k0 + r) * N_DIM + n0 + c;
#pragma unroll
    for (int j = 0; j < 4; ++j) {
      const float w = src[j];
      tile[r][c + j] = (w > 0.f) ? (unsigned short)0x3F80u
                                 : ((w < 0.f) ? (unsigned short)0xBF80u
                                              : (unsigned short)0u);
    }
  }
  __syncthreads();
  const int n  = t >> 2;
  const int kg = (t & 3) * 16;
  u16x8 o0, o1;
#pragma unroll
  for (int j = 0; j < 8; ++j) o0[j] = tile[kg + j][n];
#pragma unroll
  for (int j = 0; j < 8; ++j) o1[j] = tile[kg + 8 + j][n];
  unsigned short* dst = WbT + (size_t)(n0 + n) * K_DIM + k0 + kg;
  *(u16x8*)dst       = o0;
  *(u16x8*)(dst + 8) = o1;
}

// ---------- main GEMM: 256x256, BK=64, 8 waves ----------
// LDS = A ONLY (fused fp32->bf16, 2x32KB dbuf). B frags load global->VGPR
// (L2-resident, 64B-coalesced). 4 m201-shaped phases/tile; vm waits 12/4/12.
__global__ __launch_bounds__(512, 2) void gemm_bg(
    const float* __restrict__ X, const unsigned short* __restrict__ WbT,
    const float* __restrict__ bias, float* __restrict__ Z) {
  __shared__ __align__(16) unsigned short As[2][BM * BK];  // 64 KiB total

  const int t   = (int)threadIdx.x;
  const int l   = t & 63;
  const int wid = t >> 6;
  const int wm  = wid >> 2;  // 0..1
  const int wn  = wid & 3;   // 0..3

  const int bid = (int)blockIdx.x;
  const int swz = (bid & 7) * 32 + (bid >> 3);  // bijective: 256 = 8*32
  const int m0  = (swz >> 2) * BM;
  const int n0  = (swz & 3) * BN;

  // A fragment read offsets (XOR-swizzled; proven R1..R9)
  const int abase = (wm * 128 + (l & 15)) * BK;
  const int axk0  = (((l >> 4) + 0) ^ (l & 7)) << 3;
  const int axk1  = (((l >> 4) + 4) ^ (l & 7)) << 3;

  // A staging: thread owns rows {i*64 + t>>3}, k-granule t&7
  const float* sA0 = X + (size_t)(m0 +   0 + (t >> 3)) * K_DIM + (t & 7) * 8;
  const float* sA1 = X + (size_t)(m0 +  64 + (t >> 3)) * K_DIM + (t & 7) * 8;
  const float* sA2 = X + (size_t)(m0 + 128 + (t >> 3)) * K_DIM + (t & 7) * 8;
  const float* sA3 = X + (size_t)(m0 + 192 + (t >> 3)) * K_DIM + (t & 7) * 8;
  const int adst = (t >> 3) * BK + (((t & 7) ^ ((t >> 3) & 7)) << 3);

  // B per-lane frag pointers: row n0+wn*64+nj*16+(l&15), k-granule (l>>4)*8.
  // Wave footprint per load: 16 rows x 64B contiguous -> coalesced, L2-hit.
  const unsigned short* bp[4];
#pragma unroll
  for (int nj = 0; nj < 4; ++nj)
    bp[nj] = WbT + (size_t)(n0 + wn * 64 + nj * 16 + (l & 15)) * K_DIM +
             (l >> 4) * 8;

  f32x4 acc[8][4] = {};      // 128 acc regs
  f32x4 ar[4][2];            // A(t+1) staging (32)
  bf16x8 aF[4];              // one fragment set, reused per phase (16)
  bf16x8 bB0[4], bB1[4];     // B frags kk0 / kk1 (16+16)

#define SB0 __builtin_amdgcn_sched_barrier(0)
#define BAR do { SB0; __builtin_amdgcn_s_barrier(); SB0; } while (0)
#define WVM(N) do { asm volatile("s_waitcnt vmcnt(" #N ")" ::: "memory"); SB0; } while (0)
#define WLG0 do { asm volatile("s_waitcnt lgkmcnt(0)" ::: "memory"); SB0; } while (0)

#define LD_AST(KT)                                                         \
  do {                                                                     \
    ar[0][0] = *(const f32x4*)(sA0 + (KT));                                \
    ar[0][1] = *(const f32x4*)(sA0 + (KT) + 4);                            \
    ar[1][0] = *(const f32x4*)(sA1 + (KT));                                \
    ar[1][1] = *(const f32x4*)(sA1 + (KT) + 4);                            \
    ar[2][0] = *(const f32x4*)(sA2 + (KT));                                \
    ar[2][1] = *(const f32x4*)(sA2 + (KT) + 4);                            \
    ar[3][0] = *(const f32x4*)(sA3 + (KT));                                \
    ar[3][1] = *(const f32x4*)(sA3 + (KT) + 4);                            \
  } while (0)
#define WR_A(BUF)                                                          \
  do {                                                                     \
    _Pragma("unroll") for (int j = 0; j < 4; ++j) {                        \
      u16x8 v;                                                             \
      _Pragma("unroll") for (int q = 0; q < 4; ++q) {                      \
        v[q]     = (unsigned short)f2bf(ar[j][0][q]);                      \
        v[4 + q] = (unsigned short)f2bf(ar[j][1][q]);                      \
      }                                                                    \
      *(u16x8*)(&As[BUF][adst + j * 4096]) = v;                            \
    }                                                                      \
  } while (0)
#define LD_B4(SET, KTE)                                                    \
  do {                                                                     \
    _Pragma("unroll") for (int nj = 0; nj < 4; ++nj)                       \
      SET[nj] = *(const bf16x8*)(bp[nj] + (KTE));                          \
  } while (0)
#define RD_A4(KK, MIG, AB)                                                 \
  do {                                                                     \
    _Pragma("unroll") for (int mi = 0; mi < 4; ++mi)                       \
      aF[mi] = *(const bf16x8*)((AB) + abase + ((MIG)*4 + mi) * 1024 +     \
                                ((KK) ? axk1 : axk0));                     \
  } while (0)
#define MFMA16(MIG, BB)                                                    \
  do { __builtin_amdgcn_s_setprio(1);                                      \
    _Pragma("unroll") for (int mi = 0; mi < 4; ++mi)                       \
      _Pragma("unroll") for (int nj = 0; nj < 4; ++nj)                     \
        acc[(MIG)*4 + mi][nj] = __builtin_amdgcn_mfma_f32_16x16x32_bf16(   \
            aF[mi], BB[nj], acc[(MIG)*4 + mi][nj], 0, 0, 0);               \
    __builtin_amdgcn_s_setprio(0);                                         \
  } while (0)

  // ---- prologue: A(0)->buf0; queue = [Bk0(0):4, Ast(1):8] ----
  LD_AST(0);
  WVM(0);
  WR_A(0);
  LD_B4(bB0, 0);                 // Bk0(0)
  LD_AST(BK);                    // Ast(1)
  WLG0;                          // drain A(0) ds_writes
  BAR;

  // ---- steady: tt = 0 .. NT-3 ----
  for (int tt = 0; tt <= NT - 3; ++tt) {
    const int cur = tt & 1, nxt = cur ^ 1;
    const unsigned short* Ab = As[cur];
    const int kte = tt * BK;
    // P1 (kk0,m0): reads; issue Bk1(t); retire Bk0(t)
    RD_A4(0, 0, Ab);
    LD_B4(bB1, kte + 32);        // vm: [Bk0:4, Ast:8, Bk1:4]
    BAR; WLG0; WVM(12);          // retire Bk0(t)
    MFMA16(0, bB0);
    BAR;
    // P2 (kk0,m1)
    RD_A4(0, 1, Ab);
    BAR; WLG0;
    MFMA16(1, bB0);
    BAR;
    // P3 (kk1,m0): retire Ast(t+1); cvt+write; issue Bk0(t+1)+Ast(t+2)
    RD_A4(1, 0, Ab);
    WVM(4);                      // retire Ast(t+1); Bk1(t) stays
    WR_A(nxt);
    LD_B4(bB0, kte + BK);        // Bk0(t+1)
    LD_AST(kte + 2 * BK);        // Ast(t+2) -> vm: [Bk1:4, Bk0':4, Ast':8]
    BAR; WLG0; WVM(12);          // retire Bk1(t)
    MFMA16(0, bB1);
    BAR;
    // P4 (kk1,m1): publish nxt; cur reads all retired by WLG0
    RD_A4(1, 1, Ab);
    BAR; WLG0;
    MFMA16(1, bB1);
    BAR;
  }

  // ---- tile NT-2: steady minus Ast issue ----
  {
    const int cur = (NT - 2) & 1, nxt = cur ^ 1;
    const unsigned short* Ab = As[cur];
    const int kte = (NT - 2) * BK;
    RD_A4(0, 0, Ab);
    LD_B4(bB1, kte + 32);
    BAR; WLG0; WVM(12);
    MFMA16(0, bB0);
    BAR;
    RD_A4(0, 1, Ab);
    BAR; WLG0;
    MFMA16(1, bB0);
    BAR;
    RD_A4(1, 0, Ab);
    WVM(4);                      // retire Ast(NT-1); leaves Bk1:4
    WR_A(nxt);
    LD_B4(bB0, kte + BK);        // Bk0(NT-1) -> [Bk1:4, Bk0':4]
    BAR; WLG0; WVM(4);           // retire Bk1
    MFMA16(0, bB1);
    BAR;
    RD_A4(1, 1, Ab);
    BAR; WLG0;
    MFMA16(1, bB1);
    BAR;                         // publish NT-1 buffer
  }
  // ---- tile NT-1: pure compute ----
  {
    const unsigned short* Ab = As[(NT - 1) & 1];
    const int kte = (NT - 1) * BK;
    RD_A4(0, 0, Ab);
    LD_B4(bB1, kte + 32);        // [Bk0':4, Bk1':4]
    WLG0; WVM(4);                // retire Bk0'
    MFMA16(0, bB0);
    RD_A4(0, 1, Ab);
    WLG0;
    MFMA16(1, bB0);
    RD_A4(1, 0, Ab);
    WLG0; WVM(0);                // retire Bk1'
    MFMA16(0, bB1);
    RD_A4(1, 1, Ab);
    WLG0;
    MFMA16(1, bB1);
  }

  // ---- epilogue: + sign(bias); D frag: col = l&15, row = (l>>4)*4 + j ----
#pragma unroll
  for (int ni = 0; ni < 4; ++ni) {
    const int col = n0 + wn * 64 + ni * 16 + (l & 15);
    const float b  = bias[col];
    const float bs = (b > 0.f) ? 1.f : ((b < 0.f) ? -1.f : 0.f);
#pragma unroll
    for (int mi = 0; mi < 8; ++mi) {
      const int row = m0 + wm * 128 + mi * 16 + ((l >> 4) << 2);
#pragma unroll
      for (int j = 0; j < 4; ++j)
        Z[(size_t)(row + j) * N_DIM + col] = acc[mi][ni][j] + bs;
    }
  }
#undef SB0
#undef BAR
#undef WVM
#undef WLG0
#undef LD_AST
#undef WR_A
#undef LD_B4
#undef RD_A4
#undef MFMA16
}

// ---------- slow-but-correct fallback ----------
__global__ __launch_bounds__(256) void naive_fb(
    const float* __restrict__ X, const float* __restrict__ W,
    const float* __restrict__ bias, float* __restrict__ Z) {
  const size_t id = (size_t)blockIdx.x * 256 + threadIdx.x;
  const int m = (int)(id >> 10), n = (int)(id & 1023);
  float acc = 0.f;
  for (int k = 0; k < K_DIM; ++k) {
    const float w = W[(size_t)k * N_DIM + n];
    const float s = (w > 0.f) ? 1.f : ((w < 0.f) ? -1.f : 0.f);
    acc += X[(size_t)m * K_DIM + k] * s;
  }
  const float b = bias[n];
  Z[id] = acc + ((b > 0.f) ? 1.f : ((b < 0.f) ? -1.f : 0.f));
}

extern "C" void kernel_launch(void* const* d_in, const int* in_sizes, int n_in,
                              void* d_out, int out_size, void* d_ws, size_t ws_size,
                              hipStream_t stream) {
  const float* X    = (const float*)d_in[0];
  const float* W    = (const float*)d_in[1];
  const float* bias = (const float*)d_in[2];
  float* Z = (float*)d_out;

  const size_t needW = (size_t)N_DIM * K_DIM * sizeof(unsigned short);  // 8 MiB
  if (ws_size >= needW) {
    unsigned short* WbT = (unsigned short*)d_ws;
    wsign_transpose<<<dim3((K_DIM / 64) * (N_DIM / 64)), dim3(256), 0, stream>>>(W, WbT);
    gemm_bg<<<dim3((M_DIM / BM) * (N_DIM / BN)), dim3(512), 0, stream>>>(X, WbT, bias, Z);
  } else {
    naive_fb<<<dim3((size_t)M_DIM * N_DIM / 256), dim3(256), 0, stream>>>(X, W, bias, Z);
  }
}